// Round 4
// baseline (317.135 us; speedup 1.0000x reference)
//
#include <hip/hip_runtime.h>
#include <hip/hip_bf16.h>
#include <stdint.h>

#define SQ 4096
#define DM 1280
#define NH 16
#define HDIM 80
#define N_QKV 3840

typedef __attribute__((ext_vector_type(8))) short short8;
typedef __attribute__((ext_vector_type(4))) float f32x4;

__device__ __forceinline__ unsigned short f2bf(float f) {
  union { float f; unsigned int u; } v; v.f = f;
  unsigned int r = v.u + 0x7FFFu + ((v.u >> 16) & 1u);
  return (unsigned short)(r >> 16);
}
__device__ __forceinline__ float bf2f(unsigned short u) {
  union { unsigned int u; float f; } v; v.u = ((unsigned int)u) << 16;
  return v.f;
}

__global__ __launch_bounds__(256) void cvt_f32_bf16(const float* __restrict__ in,
                                                    unsigned short* __restrict__ out, int n4) {
  int i = blockIdx.x * blockDim.x + threadIdx.x;
  if (i >= n4) return;
  float4 v = reinterpret_cast<const float4*>(in)[i];
  ushort4 o;
  o.x = f2bf(v.x); o.y = f2bf(v.y); o.z = f2bf(v.z); o.w = f2bf(v.w);
  reinterpret_cast<ushort4*>(out)[i] = o;
}

__device__ __forceinline__ void gload_lds16(const void* g, void* l) {
  __builtin_amdgcn_global_load_lds(
      (const __attribute__((address_space(1))) void*)g,
      (__attribute__((address_space(3))) void*)l, 16, 0, 0);
}

// C[M][N] = A[M][K](bf16) * B[N][K]^T(bf16) + bias ; OUT_BF16: bf16 else f32
template <int OUT_BF16>
__global__ __launch_bounds__(256) void gemm_bt(const unsigned short* __restrict__ A,
                                               const unsigned short* __restrict__ B,
                                               const float* __restrict__ bias,
                                               void* __restrict__ C, int M, int N, int K) {
  __shared__ __align__(16) unsigned short As[128 * 32];
  __shared__ __align__(16) unsigned short Bs[128 * 32];
  const int tid = threadIdx.x;
  const int wave = tid >> 6, lane = tid & 63;
  const int r15 = lane & 15, kg = lane >> 4;
  const int wr = wave >> 1, wc = wave & 1;
  const int tm = blockIdx.y * 128, tn = blockIdx.x * 128;

  f32x4 acc[4][4];
#pragma unroll
  for (int i = 0; i < 4; ++i)
#pragma unroll
    for (int j = 0; j < 4; ++j) acc[i][j] = {0.f, 0.f, 0.f, 0.f};

  for (int kt = 0; kt < K; kt += 32) {
    __syncthreads();
#pragma unroll
    for (int j = 0; j < 2; ++j) {
      int slot = wave * 64 + lane + j * 256;     // 512 slots of 16B per tile
      int row = slot >> 2, k8 = (slot & 3) << 3;
      gload_lds16(A + (size_t)(tm + row) * K + kt + k8, &As[(wave * 64 + j * 256) * 8]);
      gload_lds16(B + (size_t)(tn + row) * K + kt + k8, &Bs[(wave * 64 + j * 256) * 8]);
    }
    __syncthreads();
    short8 af[4], bfr[4];
#pragma unroll
    for (int mi = 0; mi < 4; ++mi)
      af[mi] = *reinterpret_cast<const short8*>(&As[(wr * 64 + mi * 16 + r15) * 32 + kg * 8]);
#pragma unroll
    for (int ni = 0; ni < 4; ++ni)
      bfr[ni] = *reinterpret_cast<const short8*>(&Bs[(wc * 64 + ni * 16 + r15) * 32 + kg * 8]);
#pragma unroll
    for (int mi = 0; mi < 4; ++mi)
#pragma unroll
      for (int ni = 0; ni < 4; ++ni)
        acc[mi][ni] = __builtin_amdgcn_mfma_f32_16x16x32_bf16(af[mi], bfr[ni], acc[mi][ni], 0, 0, 0);
  }
#pragma unroll
  for (int mi = 0; mi < 4; ++mi) {
#pragma unroll
    for (int ni = 0; ni < 4; ++ni) {
      int col = tn + wc * 64 + ni * 16 + r15;
      float bv = bias[col];
#pragma unroll
      for (int r = 0; r < 4; ++r) {
        int row = tm + wr * 64 + mi * 16 + kg * 4 + r;
        float v = acc[mi][ni][r] + bv;
        if (OUT_BF16)
          ((unsigned short*)C)[(size_t)row * N + col] = f2bf(v);
        else
          ((float*)C)[(size_t)row * N + col] = v;
      }
    }
  }
}

// In-place RoPE on q,k columns of qkv[s][3840]; transpose v into Vt[h][d][s]
__global__ __launch_bounds__(256) void rope_v_kernel(unsigned short* __restrict__ qkv,
                                                     const float* __restrict__ cosb,
                                                     const float* __restrict__ sinb,
                                                     unsigned short* __restrict__ Vt) {
  int h = blockIdx.y, s0 = blockIdx.x * 64;
  __shared__ unsigned short vt[64][80];
  for (int e = threadIdx.x; e < 64 * 40; e += 256) {
    int sl = e / 40, dp = e % 40;
    int s = s0 + sl;
    float c = cosb[s * HDIM + dp];
    float sn = sinb[s * HDIM + dp];
    size_t qb = (size_t)s * N_QKV + h * HDIM;
    float q1 = bf2f(qkv[qb + dp]), q2 = bf2f(qkv[qb + dp + 40]);
    qkv[qb + dp] = f2bf(q1 * c - q2 * sn);
    qkv[qb + dp + 40] = f2bf(q2 * c + q1 * sn);
    size_t kb = qb + DM;
    float k1 = bf2f(qkv[kb + dp]), k2 = bf2f(qkv[kb + dp + 40]);
    qkv[kb + dp] = f2bf(k1 * c - k2 * sn);
    qkv[kb + dp + 40] = f2bf(k2 * c + k1 * sn);
    size_t vb = qb + 2 * DM;
    vt[sl][dp] = qkv[vb + dp];
    vt[sl][dp + 40] = qkv[vb + dp + 40];
  }
  __syncthreads();
  for (int e = threadIdx.x; e < HDIM * 64; e += 256) {
    int d = e >> 6, sl = e & 63;
    Vt[((size_t)h * HDIM + d) * SQ + s0 + sl] = vt[sl][d];
  }
}

// ---- DPP 16-lane row reductions (VALU, no LDS) ----
template <int CTRL>
__device__ __forceinline__ float dpp_f(float x) {
  int xi = __builtin_bit_cast(int, x);
  int r = __builtin_amdgcn_update_dpp(xi, xi, CTRL, 0xf, 0xf, true);
  return __builtin_bit_cast(float, r);
}
__device__ __forceinline__ float rowmax16(float x) {
  x = fmaxf(x, dpp_f<0xB1>(x));    // quad_perm [1,0,3,2]
  x = fmaxf(x, dpp_f<0x4E>(x));    // quad_perm [2,3,0,1]
  x = fmaxf(x, dpp_f<0x141>(x));   // row_half_mirror
  x = fmaxf(x, dpp_f<0x140>(x));   // row_mirror
  return x;
}
__device__ __forceinline__ float rowsum16(float x) {
  x += dpp_f<0xB1>(x);
  x += dpp_f<0x4E>(x);
  x += dpp_f<0x141>(x);
  x += dpp_f<0x140>(x);
  return x;
}

// Flash attention, block-diagonal mask.
// 2048 blocks x 128 threads (2 waves x 16 q-rows = 32 rows/block).
// XCD head clustering: block b -> xcd=b&7 serves heads {2*xcd, 2*xcd+1}
// (per-XCD working set ~2 heads' K/V/Q ~= L2-resident).
// K tile (64 keys) staged coalesced into LDS (KROW=84 -> conflict-free b64
// reads); T14 split: next tile's global loads issue before compute, LDS
// write lands after the barrier. V frags read direct from L2 (Vt layout).
__global__ __launch_bounds__(128, 4) void attn_kernel(const unsigned short* __restrict__ qkv,
                                                      const unsigned short* __restrict__ Vt,
                                                      const int* __restrict__ cu, int nseg,
                                                      unsigned short* __restrict__ attn_out) {
  constexpr int KROW = 84;   // 80 data + 4 pad shorts; word-stride 42 -> 16 distinct banks
  constexpr int PROW = 68;   // 64 data + 4 pad
  __shared__ __align__(16) unsigned short Kl[64 * KROW];     // 10752 B
  __shared__ __align__(16) unsigned short Pl[2][16 * PROW];  //  4352 B
  __shared__ int cus[32];

  const int tid = threadIdx.x;
  const int wave = tid >> 6, lane = tid & 63;
  const int r15 = lane & 15, kg = lane >> 4;
  const short8 z8 = {0, 0, 0, 0, 0, 0, 0, 0};

  const int b = blockIdx.x;
  const int xcd = b & 7, j = b >> 3;
  const int h = xcd * 2 + (j >> 7);
  const int qt2 = j & 127;            // 32-row tile index

  if (tid <= nseg) cus[tid] = cu[tid];
  __syncthreads();

  auto seg_of = [&](int pos) {
    int s2 = 0;
    for (int i2 = 1; i2 < nseg; ++i2)
      if (pos >= cus[i2]) s2 = i2;
    return s2;
  };

  const int tbase = qt2 * 32;
  const int wbase = tbase + wave * 16;
  int rs[4], re[4];
#pragma unroll
  for (int r = 0; r < 4; ++r) {
    int sg = seg_of(wbase + kg * 4 + r);
    rs[r] = cus[sg];
    re[r] = cus[sg + 1];
  }
  // block-uniform key range (union over the 32 rows) so barriers stay uniform
  const int kb0 = cus[seg_of(tbase)] & ~63;
  const int kend = cus[seg_of(tbase + 31) + 1];
  const int nt = (kend - kb0 + 63) >> 6;

  // Q A-frags
  const unsigned short* qp = qkv + (size_t)(wbase + r15) * N_QKV + h * HDIM;
  short8 qf[3];
#pragma unroll
  for (int ds = 0; ds < 3; ++ds) {
    int d0 = ds * 32 + kg * 8;
    qf[ds] = (d0 < HDIM) ? *reinterpret_cast<const short8*>(qp + d0) : z8;
  }

  float m[4] = {-1e30f, -1e30f, -1e30f, -1e30f};
  float l[4] = {0.f, 0.f, 0.f, 0.f};
  f32x4 acc[5];
#pragma unroll
  for (int dg = 0; dg < 5; ++dg) acc[dg] = {0.f, 0.f, 0.f, 0.f};

  const float scale = 0.1118033988749895f;  // 1/sqrt(80)
  const unsigned short* kbase = qkv + DM + (size_t)h * HDIM;
  const unsigned short* vbase = Vt + (size_t)h * HDIM * SQ;
  unsigned short* pw = &Pl[wave][0];

  // K tile staging: 64 rows x 160B = 10240B; 128 threads x 16B x 5 passes.
  uint4 st[5];
  auto stage_load = [&](int kb) {
#pragma unroll
    for (int c = 0; c < 5; ++c) {
      int slot = c * 128 + tid;          // 640 x 16B chunks
      int row = slot / 10, part = slot % 10;
      st[c] = *reinterpret_cast<const uint4*>(kbase + (size_t)(kb + row) * N_QKV + part * 8);
    }
  };
  auto stage_write = [&]() {
#pragma unroll
    for (int c = 0; c < 5; ++c) {
      int slot = c * 128 + tid;
      int row = slot / 10, part = slot % 10;
      unsigned short* dst = &Kl[row * KROW + part * 8];   // 8B-aligned always
      *reinterpret_cast<uint2*>(dst) = make_uint2(st[c].x, st[c].y);
      *reinterpret_cast<uint2*>(dst + 4) = make_uint2(st[c].z, st[c].w);
    }
  };

  stage_load(kb0);
  stage_write();
  __syncthreads();

  for (int t = 0; t < nt; ++t) {
    const int k0 = kb0 + (t << 6);
    if (t + 1 < nt) stage_load(k0 + 64);  // in flight across the whole step

    // ---- QK^T: 16 q-rows x 64 keys from LDS (conflict-free b64 pairs) ----
    f32x4 sa[4];
#pragma unroll
    for (int g = 0; g < 4; ++g) sa[g] = {0.f, 0.f, 0.f, 0.f};
#pragma unroll
    for (int g = 0; g < 4; ++g) {
      const unsigned short* kr = &Kl[(g * 16 + r15) * KROW];
#pragma unroll
      for (int ds = 0; ds < 3; ++ds) {
        int d0 = ds * 32 + kg * 8;
        short8 kf;
        if (d0 < HDIM) {
          union { short8 v; uint2 d[2]; } ku;
          ku.d[0] = *reinterpret_cast<const uint2*>(kr + d0);
          ku.d[1] = *reinterpret_cast<const uint2*>(kr + d0 + 4);
          kf = ku.v;
        } else {
          kf = z8;
        }
        sa[g] = __builtin_amdgcn_mfma_f32_16x16x32_bf16(qf[ds], kf, sa[g], 0, 0, 0);
      }
    }

    // ---- V frags (issue early; consumed after softmax) ----
    short8 vf[5][2];
#pragma unroll
    for (int dg = 0; dg < 5; ++dg)
#pragma unroll
      for (int g2 = 0; g2 < 2; ++g2)
        vf[dg][g2] = *reinterpret_cast<const short8*>(
            vbase + (size_t)(dg * 16 + r15) * SQ + k0 + g2 * 32 + kg * 8);

    // ---- masked online softmax (DPP over the 16-lane key axis) ----
    float p[4][4], corr[4];
#pragma unroll
    for (int r = 0; r < 4; ++r) {
      float vv[4];
#pragma unroll
      for (int g = 0; g < 4; ++g) {
        int key = k0 + g * 16 + r15;
        vv[g] = (key >= rs[r] && key < re[r]) ? sa[g][r] * scale : -1e30f;
      }
      float mx = fmaxf(fmaxf(vv[0], vv[1]), fmaxf(vv[2], vv[3]));
      mx = rowmax16(mx);
      float mn = fmaxf(m[r], mx);
      float c = __expf(m[r] - mn);
      float sm = 0.f;
#pragma unroll
      for (int g = 0; g < 4; ++g) {
        p[r][g] = __expf(vv[g] - mn);
        sm += p[r][g];
      }
      sm = rowsum16(sm);
      l[r] = l[r] * c + sm;
      m[r] = mn;
      corr[r] = c;
    }
#pragma unroll
    for (int dg = 0; dg < 5; ++dg) {
      f32x4 t2 = acc[dg];
      t2[0] *= corr[0]; t2[1] *= corr[1]; t2[2] *= corr[2]; t2[3] *= corr[3];
      acc[dg] = t2;
    }

    // ---- P (D-frag) -> A-frag via wave-private LDS (no barrier needed) ----
#pragma unroll
    for (int r = 0; r < 4; ++r) {
      unsigned short* prow = pw + (kg * 4 + r) * PROW;
#pragma unroll
      for (int g = 0; g < 4; ++g) prow[g * 16 + r15] = f2bf(p[r][g]);
    }
    asm volatile("s_waitcnt lgkmcnt(0)" ::: "memory");
    const unsigned short* prd = pw + r15 * PROW;
    union { short8 v; uint2 d[2]; } pu[2];
#pragma unroll
    for (int g2 = 0; g2 < 2; ++g2) {
      pu[g2].d[0] = *reinterpret_cast<const uint2*>(prd + g2 * 32 + kg * 8);
      pu[g2].d[1] = *reinterpret_cast<const uint2*>(prd + g2 * 32 + kg * 8 + 4);
    }

    // ---- PV ----
    __builtin_amdgcn_s_setprio(1);
#pragma unroll
    for (int dg = 0; dg < 5; ++dg)
#pragma unroll
      for (int g2 = 0; g2 < 2; ++g2)
        acc[dg] = __builtin_amdgcn_mfma_f32_16x16x32_bf16(pu[g2].v, vf[dg][g2], acc[dg], 0, 0, 0);
    __builtin_amdgcn_s_setprio(0);

    __syncthreads();                    // both waves done reading Kl[t]
    if (t + 1 < nt) stage_write();
    __syncthreads();                    // Kl[t+1] visible
  }

  // epilogue
#pragma unroll
  for (int r = 0; r < 4; ++r) {
    int row = wbase + kg * 4 + r;
    float inv = 1.0f / l[r];
#pragma unroll
    for (int dg = 0; dg < 5; ++dg)
      attn_out[(size_t)row * DM + h * HDIM + dg * 16 + r15] = f2bf(acc[dg][r] * inv);
  }
}

extern "C" void kernel_launch(void* const* d_in, const int* in_sizes, int n_in,
                              void* d_out, int out_size, void* d_ws, size_t ws_size,
                              hipStream_t stream) {
  const float* hidden = (const float*)d_in[0];
  const float* cosb = (const float*)d_in[1];
  const float* sinb = (const float*)d_in[2];
  const float* qkv_w = (const float*)d_in[3];
  const float* qkv_b = (const float*)d_in[4];
  const float* proj_w = (const float*)d_in[5];
  const float* proj_b = (const float*)d_in[6];
  const int* cu = (const int*)d_in[7];
  int nseg = in_sizes[7] - 1;
  float* out = (float*)d_out;

  char* ws = (char*)d_ws;
  unsigned short* Ah = (unsigned short*)(ws);                        // 10,485,760 B
  unsigned short* Wq = (unsigned short*)(ws + 10485760);             //  9,830,400 B
  unsigned short* Wp = (unsigned short*)(ws + 10485760 + 9830400);   //  3,276,800 B
  unsigned short* qkvB = (unsigned short*)(ws + 23592960);           // 31,457,280 B
  unsigned short* Vt = (unsigned short*)(ws + 23592960 + 31457280);  // 10,485,760 B
  unsigned short* attn_out = Ah;  // reuse (Ah dead after GEMM1)

  cvt_f32_bf16<<<dim3((1310720 + 255) / 256), dim3(256), 0, stream>>>(hidden, Ah, 1310720);
  cvt_f32_bf16<<<dim3((1228800 + 255) / 256), dim3(256), 0, stream>>>(qkv_w, Wq, 1228800);
  cvt_f32_bf16<<<dim3((409600 + 255) / 256), dim3(256), 0, stream>>>(proj_w, Wp, 409600);
  gemm_bt<1><<<dim3(30, 32), dim3(256), 0, stream>>>(Ah, Wq, qkv_b, qkvB, SQ, N_QKV, DM);
  rope_v_kernel<<<dim3(64, NH), dim3(256), 0, stream>>>(qkvB, cosb, sinb, Vt);
  attn_kernel<<<dim3(2048), dim3(128), 0, stream>>>(qkvB, Vt, cu, nseg, attn_out);
  gemm_bt<0><<<dim3(10, 32), dim3(256), 0, stream>>>(attn_out, Wp, proj_b, out, SQ, DM, DM);
}

// Round 5
// 211.838 us; speedup vs baseline: 1.4971x; 1.4971x over previous
//
#include <hip/hip_runtime.h>
#include <hip/hip_bf16.h>
#include <stdint.h>

#define SQ 4096
#define DM 1280
#define NH 16
#define HDIM 80
#define N_QKV 3840

typedef __attribute__((ext_vector_type(8))) short short8;
typedef __attribute__((ext_vector_type(4))) float f32x4;

__device__ __forceinline__ unsigned short f2bf(float f) {
  union { float f; unsigned int u; } v; v.f = f;
  unsigned int r = v.u + 0x7FFFu + ((v.u >> 16) & 1u);
  return (unsigned short)(r >> 16);
}
__device__ __forceinline__ float bf2f(unsigned short u) {
  union { unsigned int u; float f; } v; v.u = ((unsigned int)u) << 16;
  return v.f;
}

__global__ __launch_bounds__(256) void cvt_f32_bf16(const float* __restrict__ in,
                                                    unsigned short* __restrict__ out, int n4) {
  int i = blockIdx.x * blockDim.x + threadIdx.x;
  if (i >= n4) return;
  float4 v = reinterpret_cast<const float4*>(in)[i];
  ushort4 o;
  o.x = f2bf(v.x); o.y = f2bf(v.y); o.z = f2bf(v.z); o.w = f2bf(v.w);
  reinterpret_cast<ushort4*>(out)[i] = o;
}

__device__ __forceinline__ void gload_lds16(const void* g, void* l) {
  __builtin_amdgcn_global_load_lds(
      (const __attribute__((address_space(1))) void*)g,
      (__attribute__((address_space(3))) void*)l, 16, 0, 0);
}

// C[M][N] = A[M][K](bf16) * B[N][K]^T(bf16) + bias ; OUT_BF16: bf16 else f32
template <int OUT_BF16>
__global__ __launch_bounds__(256) void gemm_bt(const unsigned short* __restrict__ A,
                                               const unsigned short* __restrict__ B,
                                               const float* __restrict__ bias,
                                               void* __restrict__ C, int M, int N, int K) {
  __shared__ __align__(16) unsigned short As[128 * 32];
  __shared__ __align__(16) unsigned short Bs[128 * 32];
  const int tid = threadIdx.x;
  const int wave = tid >> 6, lane = tid & 63;
  const int r15 = lane & 15, kg = lane >> 4;
  const int wr = wave >> 1, wc = wave & 1;
  const int tm = blockIdx.y * 128, tn = blockIdx.x * 128;

  f32x4 acc[4][4];
#pragma unroll
  for (int i = 0; i < 4; ++i)
#pragma unroll
    for (int j = 0; j < 4; ++j) acc[i][j] = {0.f, 0.f, 0.f, 0.f};

  for (int kt = 0; kt < K; kt += 32) {
    __syncthreads();
#pragma unroll
    for (int j = 0; j < 2; ++j) {
      int slot = wave * 64 + lane + j * 256;     // 512 slots of 16B per tile
      int row = slot >> 2, k8 = (slot & 3) << 3;
      gload_lds16(A + (size_t)(tm + row) * K + kt + k8, &As[(wave * 64 + j * 256) * 8]);
      gload_lds16(B + (size_t)(tn + row) * K + kt + k8, &Bs[(wave * 64 + j * 256) * 8]);
    }
    __syncthreads();
    short8 af[4], bfr[4];
#pragma unroll
    for (int mi = 0; mi < 4; ++mi)
      af[mi] = *reinterpret_cast<const short8*>(&As[(wr * 64 + mi * 16 + r15) * 32 + kg * 8]);
#pragma unroll
    for (int ni = 0; ni < 4; ++ni)
      bfr[ni] = *reinterpret_cast<const short8*>(&Bs[(wc * 64 + ni * 16 + r15) * 32 + kg * 8]);
#pragma unroll
    for (int mi = 0; mi < 4; ++mi)
#pragma unroll
      for (int ni = 0; ni < 4; ++ni)
        acc[mi][ni] = __builtin_amdgcn_mfma_f32_16x16x32_bf16(af[mi], bfr[ni], acc[mi][ni], 0, 0, 0);
  }
#pragma unroll
  for (int mi = 0; mi < 4; ++mi) {
#pragma unroll
    for (int ni = 0; ni < 4; ++ni) {
      int col = tn + wc * 64 + ni * 16 + r15;
      float bv = bias[col];
#pragma unroll
      for (int r = 0; r < 4; ++r) {
        int row = tm + wr * 64 + mi * 16 + kg * 4 + r;
        float v = acc[mi][ni][r] + bv;
        if (OUT_BF16)
          ((unsigned short*)C)[(size_t)row * N + col] = f2bf(v);
        else
          ((float*)C)[(size_t)row * N + col] = v;
      }
    }
  }
}

// In-place RoPE on q,k columns of qkv[s][3840]; transpose v into Vt[h][d][s]
__global__ __launch_bounds__(256) void rope_v_kernel(unsigned short* __restrict__ qkv,
                                                     const float* __restrict__ cosb,
                                                     const float* __restrict__ sinb,
                                                     unsigned short* __restrict__ Vt) {
  int h = blockIdx.y, s0 = blockIdx.x * 64;
  __shared__ unsigned short vt[64][80];
  for (int e = threadIdx.x; e < 64 * 40; e += 256) {
    int sl = e / 40, dp = e % 40;
    int s = s0 + sl;
    float c = cosb[s * HDIM + dp];
    float sn = sinb[s * HDIM + dp];
    size_t qb = (size_t)s * N_QKV + h * HDIM;
    float q1 = bf2f(qkv[qb + dp]), q2 = bf2f(qkv[qb + dp + 40]);
    qkv[qb + dp] = f2bf(q1 * c - q2 * sn);
    qkv[qb + dp + 40] = f2bf(q2 * c + q1 * sn);
    size_t kb = qb + DM;
    float k1 = bf2f(qkv[kb + dp]), k2 = bf2f(qkv[kb + dp + 40]);
    qkv[kb + dp] = f2bf(k1 * c - k2 * sn);
    qkv[kb + dp + 40] = f2bf(k2 * c + k1 * sn);
    size_t vb = qb + 2 * DM;
    vt[sl][dp] = qkv[vb + dp];
    vt[sl][dp + 40] = qkv[vb + dp + 40];
  }
  __syncthreads();
  for (int e = threadIdx.x; e < HDIM * 64; e += 256) {
    int d = e >> 6, sl = e & 63;
    Vt[((size_t)h * HDIM + d) * SQ + s0 + sl] = vt[sl][d];
  }
}

// ---- DPP 16-lane row reductions (VALU, no LDS) ----
template <int CTRL>
__device__ __forceinline__ float dpp_f(float x) {
  int xi = __builtin_bit_cast(int, x);
  int r = __builtin_amdgcn_update_dpp(xi, xi, CTRL, 0xf, 0xf, true);
  return __builtin_bit_cast(float, r);
}
__device__ __forceinline__ float rowmax16(float x) {
  x = fmaxf(x, dpp_f<0xB1>(x));    // quad_perm [1,0,3,2]
  x = fmaxf(x, dpp_f<0x4E>(x));    // quad_perm [2,3,0,1]
  x = fmaxf(x, dpp_f<0x141>(x));   // row_half_mirror
  x = fmaxf(x, dpp_f<0x140>(x));   // row_mirror
  return x;
}
__device__ __forceinline__ float rowsum16(float x) {
  x += dpp_f<0xB1>(x);
  x += dpp_f<0x4E>(x);
  x += dpp_f<0x141>(x);
  x += dpp_f<0x140>(x);
  return x;
}

// Flash attention, block-diagonal mask.
// 1024 blocks x 256 threads (4 waves x 16 q-rows = 64 rows/block).
// XCD head clustering: xcd=b&7 serves heads {2xcd, 2xcd+1} (K/V L2-resident).
// K tile: LDS [64][256B], 16B chunks XOR-swizzled (c ^= row&7) -> conflict-free
// b128 reads; staged via global_load_lds with inverse-swizzled global source.
// V tile: LDS [80][128B], same swizzle. Double-buffered; counted vmcnt(7) +
// raw s_barrier keeps next tile's 7 loads in flight across barriers (T3/T4).
__global__ __launch_bounds__(256, 2) void attn_kernel(const unsigned short* __restrict__ qkv,
                                                      const unsigned short* __restrict__ Vt,
                                                      const int* __restrict__ cu, int nseg,
                                                      unsigned short* __restrict__ attn_out) {
  constexpr int PROW = 68;
  __shared__ __align__(16) unsigned char Kl[2][64 * 256];    // 32768 B
  __shared__ __align__(16) unsigned char Vl[2][80 * 128];    // 20480 B
  __shared__ __align__(16) unsigned short Pl[4][16 * PROW];  //  8704 B
  __shared__ int cus[32];

  const int tid = threadIdx.x;
  const int wave = tid >> 6, lane = tid & 63;
  const int r15 = lane & 15, kg = lane >> 4;
  const int s7 = r15 & 7;
  const short8 z8 = {0, 0, 0, 0, 0, 0, 0, 0};

  const int b = blockIdx.x;
  const int xcd = b & 7, j = b >> 3;       // j in 0..127
  const int h = xcd * 2 + (j >> 6);
  const int qt = j & 63;

  if (tid <= nseg) cus[tid] = cu[tid];
  __syncthreads();

  auto seg_of = [&](int pos) {
    int s2 = 0;
    for (int i2 = 1; i2 < nseg; ++i2)
      if (pos >= cus[i2]) s2 = i2;
    return s2;
  };

  const int tbase = qt * 64;
  const int wbase = tbase + wave * 16;
  int rs[4], re[4];
#pragma unroll
  for (int r = 0; r < 4; ++r) {
    int sg = seg_of(wbase + kg * 4 + r);
    rs[r] = cus[sg];
    re[r] = cus[sg + 1];
  }
  const int kb0 = cus[seg_of(tbase)] & ~63;
  const int kend = cus[seg_of(tbase + 63) + 1];
  const int nt = (kend - kb0 + 63) >> 6;

  // Q A-frags (only global loads besides staging; issued once, up front)
  const unsigned short* qp = qkv + (size_t)(wbase + r15) * N_QKV + h * HDIM;
  short8 qf[3];
#pragma unroll
  for (int ds = 0; ds < 3; ++ds) {
    int d0 = ds * 32 + kg * 8;
    qf[ds] = (d0 < HDIM) ? *reinterpret_cast<const short8*>(qp + d0) : z8;
  }

  float m[4] = {-1e30f, -1e30f, -1e30f, -1e30f};
  float l[4] = {0.f, 0.f, 0.f, 0.f};
  f32x4 acc[5];
#pragma unroll
  for (int dg = 0; dg < 5; ++dg) acc[dg] = {0.f, 0.f, 0.f, 0.f};

  const float scale = 0.1118033988749895f;  // 1/sqrt(80)
  const unsigned short* kbase = qkv + DM + (size_t)h * HDIM;
  const unsigned short* vbase = Vt + (size_t)h * HDIM * SQ;
  unsigned short* pw = &Pl[wave][0];
  const int wub = tid & ~63;  // wave*64

  // 7 global_load_lds per thread-wave per tile: K 4 passes + V 2.5 passes.
  auto issue_stage = [&](int kb, int buf) {
    unsigned char* kd = &Kl[buf][0];
    unsigned char* vd = &Vl[buf][0];
#pragma unroll
    for (int p = 0; p < 4; ++p) {            // K: 1024 chunks of 16B
      int L = p * 256 + tid;
      int row = L >> 4;
      int c = (L & 15) ^ (row & 7);          // inverse swizzle on global source
      int csrc = (c < 10) ? c : 0;           // pad chunks: load dummy (never read)
      gload_lds16(kbase + (size_t)(kb + row) * N_QKV + csrc * 8,
                  kd + (p * 256 + wub) * 16);
    }
#pragma unroll
    for (int p = 0; p < 2; ++p) {            // V: first 512 of 640 chunks
      int L = p * 256 + tid;
      int row = L >> 3;
      int c = (L & 7) ^ (row & 7);
      gload_lds16(vbase + (size_t)row * SQ + kb + c * 8,
                  vd + (p * 256 + wub) * 16);
    }
    {                                        // V: last 128 chunks, 32 lanes/wave
      int L = 512 + (wub >> 1) + (lane & 31);
      int row = L >> 3;
      int c = (L & 7) ^ (row & 7);
      if (lane < 32)
        gload_lds16(vbase + (size_t)row * SQ + kb + c * 8,
                    vd + (512 + (wub >> 1)) * 16);
    }
  };

  issue_stage(kb0, 0);
  int cur = 0;

  for (int t = 0; t < nt; ++t) {
    const int k0 = kb0 + (t << 6);
    if (t + 1 < nt) {
      issue_stage(k0 + 64, cur ^ 1);
      asm volatile("s_waitcnt vmcnt(7)" ::: "memory");  // tile t landed; t+1 in flight
    } else {
      asm volatile("s_waitcnt vmcnt(0)" ::: "memory");
    }
    __builtin_amdgcn_sched_barrier(0);
    __builtin_amdgcn_s_barrier();            // raw: no compiler vmcnt(0) drain

    const unsigned char* Kc = &Kl[cur][0];
    const unsigned char* Vc = &Vl[cur][0];

    // ---- QK^T: 16 q-rows x 64 keys (conflict-free swizzled b128) ----
    f32x4 sa[4];
#pragma unroll
    for (int g = 0; g < 4; ++g) sa[g] = {0.f, 0.f, 0.f, 0.f};
#pragma unroll
    for (int g = 0; g < 4; ++g) {
      const unsigned char* kr = Kc + ((g * 16 + r15) << 8);
#pragma unroll
      for (int ds = 0; ds < 3; ++ds) {
        int d0 = ds * 32 + kg * 8;
        short8 kf = (d0 < HDIM)
            ? *reinterpret_cast<const short8*>(kr + (((ds * 4 + kg) ^ s7) << 4))
            : z8;
        sa[g] = __builtin_amdgcn_mfma_f32_16x16x32_bf16(qf[ds], kf, sa[g], 0, 0, 0);
      }
    }

    // ---- V frags from LDS (swizzled, conflict-free) ----
    short8 vf[5][2];
#pragma unroll
    for (int dg = 0; dg < 5; ++dg)
#pragma unroll
      for (int g2 = 0; g2 < 2; ++g2)
        vf[dg][g2] = *reinterpret_cast<const short8*>(
            Vc + ((dg * 16 + r15) << 7) + (((g2 * 4 + kg) ^ s7) << 4));

    // ---- masked online softmax (DPP over the 16-lane key axis) ----
    float p[4][4], corr[4];
#pragma unroll
    for (int r = 0; r < 4; ++r) {
      float vv[4];
#pragma unroll
      for (int g = 0; g < 4; ++g) {
        int key = k0 + g * 16 + r15;
        vv[g] = (key >= rs[r] && key < re[r]) ? sa[g][r] * scale : -1e30f;
      }
      float mx = fmaxf(fmaxf(vv[0], vv[1]), fmaxf(vv[2], vv[3]));
      mx = rowmax16(mx);
      float mn = fmaxf(m[r], mx);
      float c = __expf(m[r] - mn);
      float sm = 0.f;
#pragma unroll
      for (int g = 0; g < 4; ++g) {
        p[r][g] = __expf(vv[g] - mn);
        sm += p[r][g];
      }
      sm = rowsum16(sm);
      l[r] = l[r] * c + sm;
      m[r] = mn;
      corr[r] = c;
    }
#pragma unroll
    for (int dg = 0; dg < 5; ++dg) {
      f32x4 t2 = acc[dg];
      t2[0] *= corr[0]; t2[1] *= corr[1]; t2[2] *= corr[2]; t2[3] *= corr[3];
      acc[dg] = t2;
    }

    // ---- P (D-frag) -> A-frag via wave-private LDS ----
#pragma unroll
    for (int r = 0; r < 4; ++r) {
      unsigned short* prow = pw + (kg * 4 + r) * PROW;
#pragma unroll
      for (int g = 0; g < 4; ++g) prow[g * 16 + r15] = f2bf(p[r][g]);
    }
    asm volatile("s_waitcnt lgkmcnt(0)" ::: "memory");
    __builtin_amdgcn_sched_barrier(0);
    const unsigned short* prd = pw + r15 * PROW;
    union { short8 v; uint2 d[2]; } pu[2];
#pragma unroll
    for (int g2 = 0; g2 < 2; ++g2) {
      pu[g2].d[0] = *reinterpret_cast<const uint2*>(prd + g2 * 32 + kg * 8);
      pu[g2].d[1] = *reinterpret_cast<const uint2*>(prd + g2 * 32 + kg * 8 + 4);
    }

    // ---- PV ----
    __builtin_amdgcn_s_setprio(1);
#pragma unroll
    for (int dg = 0; dg < 5; ++dg)
#pragma unroll
      for (int g2 = 0; g2 < 2; ++g2)
        acc[dg] = __builtin_amdgcn_mfma_f32_16x16x32_bf16(pu[g2].v, vf[dg][g2], acc[dg], 0, 0, 0);
    __builtin_amdgcn_s_setprio(0);

    __builtin_amdgcn_s_barrier();            // all waves done reading buf[cur]
    cur ^= 1;
  }

  // epilogue
#pragma unroll
  for (int r = 0; r < 4; ++r) {
    int row = wbase + kg * 4 + r;
    float inv = 1.0f / l[r];
#pragma unroll
    for (int dg = 0; dg < 5; ++dg)
      attn_out[(size_t)row * DM + h * HDIM + dg * 16 + r15] = f2bf(acc[dg][r] * inv);
  }
}

extern "C" void kernel_launch(void* const* d_in, const int* in_sizes, int n_in,
                              void* d_out, int out_size, void* d_ws, size_t ws_size,
                              hipStream_t stream) {
  const float* hidden = (const float*)d_in[0];
  const float* cosb = (const float*)d_in[1];
  const float* sinb = (const float*)d_in[2];
  const float* qkv_w = (const float*)d_in[3];
  const float* qkv_b = (const float*)d_in[4];
  const float* proj_w = (const float*)d_in[5];
  const float* proj_b = (const float*)d_in[6];
  const int* cu = (const int*)d_in[7];
  int nseg = in_sizes[7] - 1;
  float* out = (float*)d_out;

  char* ws = (char*)d_ws;
  unsigned short* Ah = (unsigned short*)(ws);                        // 10,485,760 B
  unsigned short* Wq = (unsigned short*)(ws + 10485760);             //  9,830,400 B
  unsigned short* Wp = (unsigned short*)(ws + 10485760 + 9830400);   //  3,276,800 B
  unsigned short* qkvB = (unsigned short*)(ws + 23592960);           // 31,457,280 B
  unsigned short* Vt = (unsigned short*)(ws + 23592960 + 31457280);  // 10,485,760 B
  unsigned short* attn_out = Ah;  // reuse (Ah dead after GEMM1)

  cvt_f32_bf16<<<dim3((1310720 + 255) / 256), dim3(256), 0, stream>>>(hidden, Ah, 1310720);
  cvt_f32_bf16<<<dim3((1228800 + 255) / 256), dim3(256), 0, stream>>>(qkv_w, Wq, 1228800);
  cvt_f32_bf16<<<dim3((409600 + 255) / 256), dim3(256), 0, stream>>>(proj_w, Wp, 409600);
  gemm_bt<1><<<dim3(30, 32), dim3(256), 0, stream>>>(Ah, Wq, qkv_b, qkvB, SQ, N_QKV, DM);
  rope_v_kernel<<<dim3(64, NH), dim3(256), 0, stream>>>(qkvB, cosb, sinb, Vt);
  attn_kernel<<<dim3(1024), dim3(256), 0, stream>>>(qkvB, Vt, cu, nseg, attn_out);
  gemm_bt<0><<<dim3(10, 32), dim3(256), 0, stream>>>(attn_out, Wp, proj_b, out, SQ, DM, DM);
}

// Round 6
// 193.714 us; speedup vs baseline: 1.6371x; 1.0936x over previous
//
#include <hip/hip_runtime.h>
#include <hip/hip_bf16.h>
#include <stdint.h>

#define SQ 4096
#define DM 1280
#define NH 16
#define HDIM 80
#define N_QKV 3840

typedef __attribute__((ext_vector_type(8))) short short8;
typedef __attribute__((ext_vector_type(4))) float f32x4;

__device__ __forceinline__ unsigned short f2bf(float f) {
  union { float f; unsigned int u; } v; v.f = f;
  unsigned int r = v.u + 0x7FFFu + ((v.u >> 16) & 1u);
  return (unsigned short)(r >> 16);
}
__device__ __forceinline__ float bf2f(unsigned short u) {
  union { unsigned int u; float f; } v; v.u = ((unsigned int)u) << 16;
  return v.f;
}

// One fused convert pass over hidden (5120 blk), qkv_w (4800 blk), proj_w (1600 blk)
__global__ __launch_bounds__(256) void cvt_all(const float* __restrict__ hidden,
                                               const float* __restrict__ qkv_w,
                                               const float* __restrict__ proj_w,
                                               unsigned short* __restrict__ oh,
                                               unsigned short* __restrict__ oq,
                                               unsigned short* __restrict__ op) {
  int b = blockIdx.x;
  const float* in;
  unsigned short* out;
  int base;
  if (b < 5120) { in = hidden; out = oh; base = b; }
  else if (b < 9920) { in = qkv_w; out = oq; base = b - 5120; }
  else { in = proj_w; out = op; base = b - 9920; }
  int i = base * 256 + threadIdx.x;
  float4 v = reinterpret_cast<const float4*>(in)[i];
  ushort4 o;
  o.x = f2bf(v.x); o.y = f2bf(v.y); o.z = f2bf(v.z); o.w = f2bf(v.w);
  reinterpret_cast<ushort4*>(out)[i] = o;
}

__device__ __forceinline__ void gload_lds16(const void* g, void* l) {
  __builtin_amdgcn_global_load_lds(
      (const __attribute__((address_space(1))) void*)g,
      (__attribute__((address_space(3))) void*)l, 16, 0, 0);
}

// C[M][N] = A[M][K](bf16) * B[N][K]^T(bf16) + bias ; OUT_BF16: bf16 else f32.
// 1D grid, nby==32 rows of 128; nbx (even) cols of 128. XCD c owns an
// 8-row x nbx/2-col rectangle of tiles (L2 locality). Depth-2 prefetch into
// 3 LDS buffers; counted vmcnt + raw s_barrier (no vmcnt(0) drain in loop).
template <int OUT_BF16>
__global__ __launch_bounds__(256, 3) void gemm_bt(const unsigned short* __restrict__ A,
                                                  const unsigned short* __restrict__ B,
                                                  const float* __restrict__ bias,
                                                  void* __restrict__ C, int M, int N, int K,
                                                  int nbx) {
  __shared__ __align__(16) unsigned short As[3][128 * 32];
  __shared__ __align__(16) unsigned short Bs[3][128 * 32];
  const int tid = threadIdx.x;
  const int wave = tid >> 6, lane = tid & 63;
  const int r15 = lane & 15, kg = lane >> 4;
  const int wr = wave >> 1, wc = wave & 1;

  // XCD rectangle remap: c = b%8 -> (rowband c&3, colband c>>2); i = b/8.
  const int b = blockIdx.x;
  const int c = b & 7, i = b >> 3;
  const int by = (c & 3) * 8 + (i & 7);
  const int bx = (c >> 2) * (nbx >> 1) + (i >> 3);
  const int tm = by * 128, tn = bx * 128;

  f32x4 acc[4][4];
#pragma unroll
  for (int x = 0; x < 4; ++x)
#pragma unroll
    for (int j = 0; j < 4; ++j) acc[x][j] = {0.f, 0.f, 0.f, 0.f};

  // per-thread staging geometry (constant across tiles)
  const int slot0 = wave * 64 + lane;
  const int row0 = slot0 >> 2, k80 = (slot0 & 3) << 3;
  const int slot1 = slot0 + 256;
  const int row1 = slot1 >> 2, k81 = (slot1 & 3) << 3;
  const unsigned short* Arow0 = A + (size_t)(tm + row0) * K + k80;
  const unsigned short* Arow1 = A + (size_t)(tm + row1) * K + k81;
  const unsigned short* Brow0 = B + (size_t)(tn + row0) * K + k80;
  const unsigned short* Brow1 = B + (size_t)(tn + row1) * K + k81;
  const int ldsoff0 = (wave * 64) * 8;         // shorts
  const int ldsoff1 = (wave * 64 + 256) * 8;

  auto stage = [&](int kt, int buf) {
    gload_lds16(Arow0 + kt, &As[buf][ldsoff0]);
    gload_lds16(Arow1 + kt, &As[buf][ldsoff1]);
    gload_lds16(Brow0 + kt, &Bs[buf][ldsoff0]);
    gload_lds16(Brow1 + kt, &Bs[buf][ldsoff1]);
  };

  const int nk = K >> 5;  // K/32 (1280 -> 40)
  stage(0, 0);
  if (nk > 1) stage(32, 1);

  int buf = 0;
  for (int t = 0; t < nk; ++t) {
    if (t + 2 < nk) {
      stage((t + 2) << 5, (buf + 2) % 3);
      asm volatile("s_waitcnt vmcnt(8)" ::: "memory");   // tile t landed
    } else if (t + 1 < nk) {
      asm volatile("s_waitcnt vmcnt(4)" ::: "memory");
    } else {
      asm volatile("s_waitcnt vmcnt(0)" ::: "memory");
    }
    __builtin_amdgcn_sched_barrier(0);
    __builtin_amdgcn_s_barrier();               // tile t visible to all waves

    short8 af[4], bfr[4];
#pragma unroll
    for (int mi = 0; mi < 4; ++mi)
      af[mi] = *reinterpret_cast<const short8*>(&As[buf][(wr * 64 + mi * 16 + r15) * 32 + kg * 8]);
#pragma unroll
    for (int ni = 0; ni < 4; ++ni)
      bfr[ni] = *reinterpret_cast<const short8*>(&Bs[buf][(wc * 64 + ni * 16 + r15) * 32 + kg * 8]);
    __builtin_amdgcn_s_setprio(1);
#pragma unroll
    for (int mi = 0; mi < 4; ++mi)
#pragma unroll
      for (int ni = 0; ni < 4; ++ni)
        acc[mi][ni] = __builtin_amdgcn_mfma_f32_16x16x32_bf16(af[mi], bfr[ni], acc[mi][ni], 0, 0, 0);
    __builtin_amdgcn_s_setprio(0);

    __builtin_amdgcn_s_barrier();               // all waves done with buf
    __builtin_amdgcn_sched_barrier(0);          // keep next stage below barrier
    buf = (buf + 1) % 3;
  }

#pragma unroll
  for (int mi = 0; mi < 4; ++mi) {
#pragma unroll
    for (int ni = 0; ni < 4; ++ni) {
      int col = tn + wc * 64 + ni * 16 + r15;
      float bv = bias[col];
#pragma unroll
      for (int r = 0; r < 4; ++r) {
        int row = tm + wr * 64 + mi * 16 + kg * 4 + r;
        float v = acc[mi][ni][r] + bv;
        if (OUT_BF16)
          ((unsigned short*)C)[(size_t)row * N + col] = f2bf(v);
        else
          ((float*)C)[(size_t)row * N + col] = v;
      }
    }
  }
}

// In-place RoPE on q,k columns of qkv[s][3840]; transpose v into Vt[h][d][s]
__global__ __launch_bounds__(256) void rope_v_kernel(unsigned short* __restrict__ qkv,
                                                     const float* __restrict__ cosb,
                                                     const float* __restrict__ sinb,
                                                     unsigned short* __restrict__ Vt) {
  int h = blockIdx.y, s0 = blockIdx.x * 64;
  __shared__ unsigned short vt[64][80];
  for (int e = threadIdx.x; e < 64 * 40; e += 256) {
    int sl = e / 40, dp = e % 40;
    int s = s0 + sl;
    float c = cosb[s * HDIM + dp];
    float sn = sinb[s * HDIM + dp];
    size_t qb = (size_t)s * N_QKV + h * HDIM;
    float q1 = bf2f(qkv[qb + dp]), q2 = bf2f(qkv[qb + dp + 40]);
    qkv[qb + dp] = f2bf(q1 * c - q2 * sn);
    qkv[qb + dp + 40] = f2bf(q2 * c + q1 * sn);
    size_t kb = qb + DM;
    float k1 = bf2f(qkv[kb + dp]), k2 = bf2f(qkv[kb + dp + 40]);
    qkv[kb + dp] = f2bf(k1 * c - k2 * sn);
    qkv[kb + dp + 40] = f2bf(k2 * c + k1 * sn);
    size_t vb = qb + 2 * DM;
    vt[sl][dp] = qkv[vb + dp];
    vt[sl][dp + 40] = qkv[vb + dp + 40];
  }
  __syncthreads();
  for (int e = threadIdx.x; e < HDIM * 64; e += 256) {
    int d = e >> 6, sl = e & 63;
    Vt[((size_t)h * HDIM + d) * SQ + s0 + sl] = vt[sl][d];
  }
}

// ---- DPP 16-lane row reductions (VALU, no LDS) ----
template <int CTRL>
__device__ __forceinline__ float dpp_f(float x) {
  int xi = __builtin_bit_cast(int, x);
  int r = __builtin_amdgcn_update_dpp(xi, xi, CTRL, 0xf, 0xf, true);
  return __builtin_bit_cast(float, r);
}
__device__ __forceinline__ float rowmax16(float x) {
  x = fmaxf(x, dpp_f<0xB1>(x));    // quad_perm [1,0,3,2]
  x = fmaxf(x, dpp_f<0x4E>(x));    // quad_perm [2,3,0,1]
  x = fmaxf(x, dpp_f<0x141>(x));   // row_half_mirror
  x = fmaxf(x, dpp_f<0x140>(x));   // row_mirror
  return x;
}
__device__ __forceinline__ float rowsum16(float x) {
  x += dpp_f<0xB1>(x);
  x += dpp_f<0x4E>(x);
  x += dpp_f<0x141>(x);
  x += dpp_f<0x140>(x);
  return x;
}

// Flash attention, block-diagonal mask. (unchanged from round 5 — verified)
__global__ __launch_bounds__(256, 2) void attn_kernel(const unsigned short* __restrict__ qkv,
                                                      const unsigned short* __restrict__ Vt,
                                                      const int* __restrict__ cu, int nseg,
                                                      unsigned short* __restrict__ attn_out) {
  constexpr int PROW = 68;
  __shared__ __align__(16) unsigned char Kl[2][64 * 256];    // 32768 B
  __shared__ __align__(16) unsigned char Vl[2][80 * 128];    // 20480 B
  __shared__ __align__(16) unsigned short Pl[4][16 * PROW];  //  8704 B
  __shared__ int cus[32];

  const int tid = threadIdx.x;
  const int wave = tid >> 6, lane = tid & 63;
  const int r15 = lane & 15, kg = lane >> 4;
  const int s7 = r15 & 7;
  const short8 z8 = {0, 0, 0, 0, 0, 0, 0, 0};

  const int b = blockIdx.x;
  const int xcd = b & 7, j = b >> 3;       // j in 0..127
  const int h = xcd * 2 + (j >> 6);
  const int qt = j & 63;

  if (tid <= nseg) cus[tid] = cu[tid];
  __syncthreads();

  auto seg_of = [&](int pos) {
    int s2 = 0;
    for (int i2 = 1; i2 < nseg; ++i2)
      if (pos >= cus[i2]) s2 = i2;
    return s2;
  };

  const int tbase = qt * 64;
  const int wbase = tbase + wave * 16;
  int rs[4], re[4];
#pragma unroll
  for (int r = 0; r < 4; ++r) {
    int sg = seg_of(wbase + kg * 4 + r);
    rs[r] = cus[sg];
    re[r] = cus[sg + 1];
  }
  const int kb0 = cus[seg_of(tbase)] & ~63;
  const int kend = cus[seg_of(tbase + 63) + 1];
  const int nt = (kend - kb0 + 63) >> 6;

  const unsigned short* qp = qkv + (size_t)(wbase + r15) * N_QKV + h * HDIM;
  short8 qf[3];
#pragma unroll
  for (int ds = 0; ds < 3; ++ds) {
    int d0 = ds * 32 + kg * 8;
    qf[ds] = (d0 < HDIM) ? *reinterpret_cast<const short8*>(qp + d0) : z8;
  }

  float m[4] = {-1e30f, -1e30f, -1e30f, -1e30f};
  float l[4] = {0.f, 0.f, 0.f, 0.f};
  f32x4 acc[5];
#pragma unroll
  for (int dg = 0; dg < 5; ++dg) acc[dg] = {0.f, 0.f, 0.f, 0.f};

  const float scale = 0.1118033988749895f;  // 1/sqrt(80)
  const unsigned short* kbase = qkv + DM + (size_t)h * HDIM;
  const unsigned short* vbase = Vt + (size_t)h * HDIM * SQ;
  unsigned short* pw = &Pl[wave][0];
  const int wub = tid & ~63;  // wave*64

  auto issue_stage = [&](int kb, int buf) {
    unsigned char* kd = &Kl[buf][0];
    unsigned char* vd = &Vl[buf][0];
#pragma unroll
    for (int p = 0; p < 4; ++p) {            // K: 1024 chunks of 16B
      int L = p * 256 + tid;
      int row = L >> 4;
      int c = (L & 15) ^ (row & 7);          // inverse swizzle on global source
      int csrc = (c < 10) ? c : 0;           // pad chunks: load dummy (never read)
      gload_lds16(kbase + (size_t)(kb + row) * N_QKV + csrc * 8,
                  kd + (p * 256 + wub) * 16);
    }
#pragma unroll
    for (int p = 0; p < 2; ++p) {            // V: first 512 of 640 chunks
      int L = p * 256 + tid;
      int row = L >> 3;
      int c = (L & 7) ^ (row & 7);
      gload_lds16(vbase + (size_t)row * SQ + kb + c * 8,
                  vd + (p * 256 + wub) * 16);
    }
    {                                        // V: last 128 chunks, 32 lanes/wave
      int L = 512 + (wub >> 1) + (lane & 31);
      int row = L >> 3;
      int c = (L & 7) ^ (row & 7);
      if (lane < 32)
        gload_lds16(vbase + (size_t)row * SQ + kb + c * 8,
                    vd + (512 + (wub >> 1)) * 16);
    }
  };

  issue_stage(kb0, 0);
  int cur = 0;

  for (int t = 0; t < nt; ++t) {
    const int k0 = kb0 + (t << 6);
    if (t + 1 < nt) {
      issue_stage(k0 + 64, cur ^ 1);
      asm volatile("s_waitcnt vmcnt(7)" ::: "memory");  // tile t landed; t+1 in flight
    } else {
      asm volatile("s_waitcnt vmcnt(0)" ::: "memory");
    }
    __builtin_amdgcn_sched_barrier(0);
    __builtin_amdgcn_s_barrier();            // raw: no compiler vmcnt(0) drain

    const unsigned char* Kc = &Kl[cur][0];
    const unsigned char* Vc = &Vl[cur][0];

    f32x4 sa[4];
#pragma unroll
    for (int g = 0; g < 4; ++g) sa[g] = {0.f, 0.f, 0.f, 0.f};
#pragma unroll
    for (int g = 0; g < 4; ++g) {
      const unsigned char* kr = Kc + ((g * 16 + r15) << 8);
#pragma unroll
      for (int ds = 0; ds < 3; ++ds) {
        int d0 = ds * 32 + kg * 8;
        short8 kf = (d0 < HDIM)
            ? *reinterpret_cast<const short8*>(kr + (((ds * 4 + kg) ^ s7) << 4))
            : z8;
        sa[g] = __builtin_amdgcn_mfma_f32_16x16x32_bf16(qf[ds], kf, sa[g], 0, 0, 0);
      }
    }

    short8 vf[5][2];
#pragma unroll
    for (int dg = 0; dg < 5; ++dg)
#pragma unroll
      for (int g2 = 0; g2 < 2; ++g2)
        vf[dg][g2] = *reinterpret_cast<const short8*>(
            Vc + ((dg * 16 + r15) << 7) + (((g2 * 4 + kg) ^ s7) << 4));

    float p[4][4], corr[4];
#pragma unroll
    for (int r = 0; r < 4; ++r) {
      float vv[4];
#pragma unroll
      for (int g = 0; g < 4; ++g) {
        int key = k0 + g * 16 + r15;
        vv[g] = (key >= rs[r] && key < re[r]) ? sa[g][r] * scale : -1e30f;
      }
      float mx = fmaxf(fmaxf(vv[0], vv[1]), fmaxf(vv[2], vv[3]));
      mx = rowmax16(mx);
      float mn = fmaxf(m[r], mx);
      float c = __expf(m[r] - mn);
      float sm = 0.f;
#pragma unroll
      for (int g = 0; g < 4; ++g) {
        p[r][g] = __expf(vv[g] - mn);
        sm += p[r][g];
      }
      sm = rowsum16(sm);
      l[r] = l[r] * c + sm;
      m[r] = mn;
      corr[r] = c;
    }
#pragma unroll
    for (int dg = 0; dg < 5; ++dg) {
      f32x4 t2 = acc[dg];
      t2[0] *= corr[0]; t2[1] *= corr[1]; t2[2] *= corr[2]; t2[3] *= corr[3];
      acc[dg] = t2;
    }

#pragma unroll
    for (int r = 0; r < 4; ++r) {
      unsigned short* prow = pw + (kg * 4 + r) * PROW;
#pragma unroll
      for (int g = 0; g < 4; ++g) prow[g * 16 + r15] = f2bf(p[r][g]);
    }
    asm volatile("s_waitcnt lgkmcnt(0)" ::: "memory");
    __builtin_amdgcn_sched_barrier(0);
    const unsigned short* prd = pw + r15 * PROW;
    union { short8 v; uint2 d[2]; } pu[2];
#pragma unroll
    for (int g2 = 0; g2 < 2; ++g2) {
      pu[g2].d[0] = *reinterpret_cast<const uint2*>(prd + g2 * 32 + kg * 8);
      pu[g2].d[1] = *reinterpret_cast<const uint2*>(prd + g2 * 32 + kg * 8 + 4);
    }

    __builtin_amdgcn_s_setprio(1);
#pragma unroll
    for (int dg = 0; dg < 5; ++dg)
#pragma unroll
      for (int g2 = 0; g2 < 2; ++g2)
        acc[dg] = __builtin_amdgcn_mfma_f32_16x16x32_bf16(pu[g2].v, vf[dg][g2], acc[dg], 0, 0, 0);
    __builtin_amdgcn_s_setprio(0);

    __builtin_amdgcn_s_barrier();            // all waves done reading buf[cur]
    cur ^= 1;
  }

#pragma unroll
  for (int r = 0; r < 4; ++r) {
    int row = wbase + kg * 4 + r;
    float inv = 1.0f / l[r];
#pragma unroll
    for (int dg = 0; dg < 5; ++dg)
      attn_out[(size_t)row * DM + h * HDIM + dg * 16 + r15] = f2bf(acc[dg][r] * inv);
  }
}

extern "C" void kernel_launch(void* const* d_in, const int* in_sizes, int n_in,
                              void* d_out, int out_size, void* d_ws, size_t ws_size,
                              hipStream_t stream) {
  const float* hidden = (const float*)d_in[0];
  const float* cosb = (const float*)d_in[1];
  const float* sinb = (const float*)d_in[2];
  const float* qkv_w = (const float*)d_in[3];
  const float* qkv_b = (const float*)d_in[4];
  const float* proj_w = (const float*)d_in[5];
  const float* proj_b = (const float*)d_in[6];
  const int* cu = (const int*)d_in[7];
  int nseg = in_sizes[7] - 1;
  float* out = (float*)d_out;

  char* ws = (char*)d_ws;
  unsigned short* Ah = (unsigned short*)(ws);                        // 10,485,760 B
  unsigned short* Wq = (unsigned short*)(ws + 10485760);             //  9,830,400 B
  unsigned short* Wp = (unsigned short*)(ws + 10485760 + 9830400);   //  3,276,800 B
  unsigned short* qkvB = (unsigned short*)(ws + 23592960);           // 31,457,280 B
  unsigned short* Vt = (unsigned short*)(ws + 23592960 + 31457280);  // 10,485,760 B
  unsigned short* attn_out = Ah;  // reuse (Ah dead after GEMM1)

  cvt_all<<<dim3(11520), dim3(256), 0, stream>>>(hidden, qkv_w, proj_w, Ah, Wq, Wp);
  gemm_bt<1><<<dim3(960), dim3(256), 0, stream>>>(Ah, Wq, qkv_b, qkvB, SQ, N_QKV, DM, 30);
  rope_v_kernel<<<dim3(64, NH), dim3(256), 0, stream>>>(qkvB, cosb, sinb, Vt);
  attn_kernel<<<dim3(1024), dim3(256), 0, stream>>>(qkvB, Vt, cu, nseg, attn_out);
  gemm_bt<0><<<dim3(320), dim3(256), 0, stream>>>(attn_out, Wp, proj_b, out, SQ, DM, DM, 10);
}